// Round 7
// baseline (278.135 us; speedup 1.0000x reference)
//
#include <hip/hip_runtime.h>

// Separable 5x5 Gaussian blur, sigma=1.1, BORDER_REFLECT_101, NHWC fp32.
// Shape: (64, 384, 512, 3). Row = 512*3 = 1536 floats = 384 float4.
// NOTE: horizontal taps are stride-3 in floats (per-channel, C=3).
//
// Small-block high-residency version. One block = 4 waves (256 thr),
// 16KB LDS, covering a HALF row-span (192 float4 cols) x 12 rows
// (3 tiles of 4). Grid = 64 batch x 32 strips x 2 halves = 4096 blocks
// -> 8 RESIDENT blocks/CU (thread cap; LDS 8x16KB=128KB<=160KB), twice
// r4's block-level heterogeneity: when one block is in its load-drought
// tail, co-resident blocks are in prologue issuing 12-16 loads, so the
// CU keeps memory requests in flight (the kernel is MLP-bound: r5/r6
// counters show no pipe saturated and input L3-resident).
// Per-wave structure identical to the proven r4: wave owns 48 output
// float4 cols (global q0), loads a 64-col window (q0-2..q0+61, halo
// included) into a register sliding window; pinned prefetch keeps the
// pipeline 2 tiles deep (prologue pins 12 rows; iter 0 issues tile 2's
// 4 rows before computing tile 0; sched_barrier(0) forbids sinking).
// Vertical sums -> wave-PRIVATE LDS strip (serial reuse, same-wave
// lgkmcnt ordering, NO __syncthreads anywhere); reflect-101 horizontal
// pads fixed from the wave's own data; horizontal pass (lanes 0..47)
// reads same-wave LDS only. 16 row-loads / 12 output rows = 1.33x read
// demand (L3-absorbed). Nontemporal stores (write-ideal per r5/r6
// counters); XCD swizzle keeps adjacent halves/strips on one XCD's L2.

#define BN 64
#define HN 384
#define WN 512
#define CN 3
#define ROWF (WN * CN)              // 1536 floats per row
#define ROWQ (ROWF / 4)             // 384 float4 per row
#define TH 4                        // rows per tile
#define NITER 3                     // tiles per block
#define SROWS (TH * NITER)          // 12 rows per block
#define NSTRIP (HN / SROWS)         // 32 strips per image
#define NHALF 2                     // column halves per row-span
#define NTHR 256                    // 4 waves per block
#define NBLK (BN * NSTRIP * NHALF)  // 4096 blocks

// Gaussian taps for ksize=5, sigma=1.1 (precomputed, normalized):
#define CW0 0.07076630f
#define CW1 0.24446040f
#define CW2 0.36954650f

// Native clang vector type: __builtin_nontemporal_store requires it.
typedef float vfloat4 __attribute__((ext_vector_type(4)));

__device__ __forceinline__ void vpass(const float4* win, float* vw, int l) {
#pragma unroll
    for (int r = 0; r < TH; ++r) {
        float4 a;
        a.x = CW0 * (win[r].x + win[r + 4].x) +
              CW1 * (win[r + 1].x + win[r + 3].x) + CW2 * win[r + 2].x;
        a.y = CW0 * (win[r].y + win[r + 4].y) +
              CW1 * (win[r + 1].y + win[r + 3].y) + CW2 * win[r + 2].y;
        a.z = CW0 * (win[r].z + win[r + 4].z) +
              CW1 * (win[r + 1].z + win[r + 3].z) + CW2 * win[r + 2].z;
        a.w = CW0 * (win[r].w + win[r + 4].w) +
              CW1 * (win[r + 1].w + win[r + 3].w) + CW2 * win[r + 2].w;
        ((float4*)(vw + r * 256))[l] = a;
    }
}

__device__ __forceinline__ void pads(float* vw, int q0, int l) {
    // reflect101 horizontal pads, window-float indexed (wf = g - 4*q0 + 8):
    //   q0==0:   g=-6..-1 <- {6,7,8,3,4,5}          => wf 2..7 <- {14,15,16,11,12,13}
    //   q0==336: g=1536..1541 <- {1530..32,1527..29} => wf 200..205 <- {194,195,196,191,192,193}
    if (q0 == 0 && l < TH * 6) {
        int r = l / 6, p = l - 6 * r;
        float* vr = vw + r * 256;
        vr[2 + p] = vr[p < 3 ? 14 + p : 8 + p];
    } else if (q0 == 336 && l < TH * 6) {
        int r = l / 6, p = l - 6 * r;
        float* vr = vw + r * 256;
        vr[200 + p] = vr[p < 3 ? 194 + p : 188 + p];
    }
}

__device__ __forceinline__ void hpass(const float* vw, float* ob, int q0, int l) {
    if (l < 48) {
#pragma unroll
        for (int r = 0; r < TH; ++r) {
            const float* vr = vw + r * 256;
            float wnd[20];                 // window floats 4l .. 4l+19
#pragma unroll
            for (int k = 0; k < 5; ++k) {
                float4 t = ((const float4*)vr)[l + k];
                wnd[4 * k + 0] = t.x;
                wnd[4 * k + 1] = t.y;
                wnd[4 * k + 2] = t.z;
                wnd[4 * k + 3] = t.w;
            }
            vfloat4 res;
#pragma unroll
            for (int j = 0; j < 4; ++j) {   // stride-3 taps: per-channel
                res[j] =
                    CW0 * (wnd[j + 2] + wnd[j + 14]) +
                    CW1 * (wnd[j + 5] + wnd[j + 11]) +
                    CW2 * wnd[j + 8];
            }
            __builtin_nontemporal_store(res,
                &((vfloat4*)ob)[r * ROWQ + q0 + l]);
        }
    }
}

__global__ __launch_bounds__(NTHR, 8) void gauss_blur_fused(
        const float* __restrict__ x, float* __restrict__ out) {
    // 4 waves * 4 rows * 256 floats = 16384 B, wave-private strips
    __shared__ float v[4 * TH * 256];

    // XCD-contiguous swizzle: XCD k (blockIdx%8) gets ids [512k, 512k+512)
    // in linear order -> both halves of a strip + vertically adjacent
    // strips (shared halo rows) run on the same XCD's L2.
    const int bid  = blockIdx.x;
    const int id   = (bid & 7) * (NBLK >> 3) + (bid >> 3);
    const int b    = id >> 6;            // id / (NSTRIP*NHALF)
    const int rem  = id & 63;
    const int s    = rem >> 1;           // strip 0..31
    const int half = rem & 1;            // column half 0/1
    const int h0   = s * SROWS;
    const float* __restrict__ xb = x + (size_t)b * HN * ROWF;
    float* __restrict__ ob = out + ((size_t)b * HN + h0) * ROWF;

    const int wid = threadIdx.x >> 6;    // wave 0..3
    const int l   = threadIdx.x & 63;    // lane
    const int q0  = half * 192 + wid * 48;   // global first output col
    int c = q0 - 2 + l;                  // this lane's window column
    c = c < 0 ? 0 : (c > ROWQ - 1 ? ROWQ - 1 : c);   // clamp (pads fix edges)

    // ---- prologue: pin 12 row-loads (tile0 window + tile1's new rows)
    float4 win[8], nxt[TH];
#pragma unroll
    for (int i = 0; i < 8; ++i) {
        int hs = h0 + i - 2;
        hs = hs < 0 ? -hs : hs;                 // reflect101 low (uniform)
        win[i] = ((const float4*)(xb + (size_t)hs * ROWF))[c];
    }
#pragma unroll
    for (int i = 0; i < TH; ++i) {
        int hs = h0 + 6 + i;                    // rows h0+6..h0+9 (<=381)
        nxt[i] = ((const float4*)(xb + (size_t)hs * ROWF))[c];
    }
    __builtin_amdgcn_sched_barrier(0);   // forbid sinking the loads

    float* const vw = v + wid * (TH * 256);   // wave's private LDS strip

#pragma unroll
    for (int t = 0; t < NITER; ++t) {
        // issue tile t+2's 4 row-loads before computing tile t
        float4 nn[TH];
        if (t < NITER - 2) {
            const int rb = h0 + 4 * t + 10;
#pragma unroll
            for (int i = 0; i < TH; ++i) {
                int hs = rb + i;
                hs = hs >= HN ? 2 * HN - 2 - hs : hs;   // reflect101 high
                nn[i] = ((const float4*)(xb + (size_t)hs * ROWF))[c];
            }
            __builtin_amdgcn_sched_barrier(0);
        }

        vpass(win, vw, l);
        pads(vw, q0, l);
        hpass(vw, ob + t * TH * ROWF, q0, l);

        // slide the register window down one tile
        if (t < NITER - 1) {
#pragma unroll
            for (int i = 0; i < TH; ++i) win[i] = win[i + 4];
#pragma unroll
            for (int i = 0; i < TH; ++i) win[TH + i] = nxt[i];
        }
        if (t < NITER - 2) {
#pragma unroll
            for (int i = 0; i < TH; ++i) nxt[i] = nn[i];
        }
    }
}

extern "C" void kernel_launch(void* const* d_in, const int* in_sizes, int n_in,
                              void* d_out, int out_size, void* d_ws, size_t ws_size,
                              hipStream_t stream) {
    const float* x = (const float*)d_in[0];
    float* out = (float*)d_out;
    gauss_blur_fused<<<dim3(NBLK), dim3(NTHR), 0, stream>>>(x, out);
}

// Round 8
// 269.131 us; speedup vs baseline: 1.0335x; 1.0335x over previous
//
#include <hip/hip_runtime.h>

// Separable 5x5 Gaussian blur, sigma=1.1, BORDER_REFLECT_101, NHWC fp32.
// Shape: (64, 384, 512, 3). Row = 512*3 = 1536 floats = 384 float4.
// Horizontal taps are stride-3 floats (per-channel, C=3).
//
// Horizontal-FIRST, all-register version (no LDS, no shuffles, no
// barriers, all 384 lanes active everywhere). For output float4 col q,
// the 5 horizontal taps are the float4s at UNALIGNED float offsets
// 4q-6, 4q-3, 4q, 4q+3, 4q+6: tap k's component j feeds output
// component j, so h-blur = 5 dword-aligned global_load_dwordx4 + pure
// vector FMA with zero repacking. Neighbor lanes' taps overlap within
// the same cache lines -> the 5x request amplification is L1-served;
// HBM still reads each line once. Vertical pass: per-lane sliding
// window of h-blurred rows in registers.
// Image-edge horizontal reflect101: lanes 0,1,382,383 recompute their
// 4 components from the clamped loads via hand-derived static selects
// (verified against the reflect tables {6,7,8,3,4,5}/{1530..32,1527..29}).
// Vertical reflect101 is wave-uniform on row pointers.
// Macro-shape = proven r4 granularity: one block per (batch, 8-row
// strip), 384 threads, grid 3072; loads pinned 2 rows ahead with
// sched_barrier(0) (r4-proven). Nontemporal full-width stores; XCD
// swizzle keeps vertically adjacent strips on one XCD's L2.

#define BN 64
#define HN 384
#define WN 512
#define CN 3
#define ROWF (WN * CN)              // 1536 floats per row
#define ROWQ (ROWF / 4)             // 384 float4 per row
#define TOUT 8                      // output rows per block
#define NROWS (TOUT + 4)            // 12 input rows per block
#define NSTR (HN / TOUT)            // 48 strips per image
#define NT 384                      // one thread per float4 column
#define NBLK (BN * NSTR)            // 3072 blocks

// Gaussian taps for ksize=5, sigma=1.1 (precomputed, normalized):
#define CW0 0.07076630f
#define CW1 0.24446040f
#define CW2 0.36954650f

typedef float vfloat4 __attribute__((ext_vector_type(4)));
// 4-byte-aligned float4 for unaligned (dword-aligned) tap loads:
typedef float f4u __attribute__((ext_vector_type(4), aligned(4)));

__global__ __launch_bounds__(NT, 3) void gauss_blur_fused(
        const float* __restrict__ x, float* __restrict__ out) {
    // XCD-contiguous strip swizzle: XCD k (blockIdx%8) gets strips
    // [k*384, (k+1)*384) in linear order.
    const int bid = blockIdx.x;
    const int id  = (bid & 7) * (NBLK >> 3) + (bid >> 3);
    const int b   = id / NSTR;
    const int h0  = (id - b * NSTR) * TOUT;
    const float* __restrict__ xb = x + (size_t)b * HN * ROWF;
    float* __restrict__ ob = out + ((size_t)b * HN + h0) * ROWF;
    const int q = threadIdx.x;           // float4 column 0..383

    // 5 horizontal tap offsets (floats), clamped into the row; the 4
    // boundary lanes get component-exact fixups below.
    int off[5];
#pragma unroll
    for (int k = 0; k < 5; ++k) {
        int o = 4 * q + 3 * k - 6;
        off[k] = o < 0 ? 0 : (o > ROWF - 4 ? ROWF - 4 : o);
    }

    // wave-uniform input row pointers (vertical reflect101)
    const float* rp[NROWS];
#pragma unroll
    for (int i = 0; i < NROWS; ++i) {
        int hr = h0 + i - 2;
        hr = hr < 0 ? -hr : hr;                 // reflect101 low
        hr = hr >= HN ? 2 * HN - 2 - hr : hr;   // reflect101 high
        rp[i] = xb + (size_t)hr * ROWF;
    }

    vfloat4 t[3][5];                     // 3-slot rotating load buffers
    vfloat4 h[NROWS];                    // h-blurred rows (live window: 5)

#define ISSUE(s, i) do { _Pragma("unroll") \
    for (int k = 0; k < 5; ++k) \
        t[s][k] = (vfloat4)(*(const f4u*)(rp[i] + off[k])); } while (0)

    // prologue: 2 rows of loads in flight before any compute
    ISSUE(0, 0);
    ISSUE(1, 1);
    __builtin_amdgcn_sched_barrier(0);

#pragma unroll
    for (int i = 0; i < NROWS; ++i) {
        // keep the pipeline 2 rows deep: issue row i+2 before using row i
        if (i + 2 < NROWS) {
            ISSUE((i + 2) % 3, i + 2);
            __builtin_amdgcn_sched_barrier(0);
        }
        const int s = i % 3;
        vfloat4 hb = CW0 * (t[s][0] + t[s][4]) +
                     CW1 * (t[s][1] + t[s][3]) +
                     CW2 * t[s][2];
        // ---- horizontal reflect101 fixups, 4 lanes, static components.
        // q=0:  off=(0,0,0,3,6):   t2=f[0..3]  t3=f[3..6]   t4=f[6..9]
        // q=1:  off=(0,1,4,7,10):  t0=f[0..3]  t1=f[1..4]   t2=f[4..7]  t3=f[7..10] t4=f[10..13]
        // q=382:off=(1522,25,28,31,32): t4=f[1532..35]
        // q=383:off=(1526,29,32,32,32): t2=t3=t4=f[1532..35]
        if (q == 0) {
            hb[0] = 2*CW0*t[s][4][0] + 2*CW1*t[s][3][0] + CW2*t[s][2][0];
            hb[1] = 2*CW0*t[s][4][1] + 2*CW1*t[s][3][1] + CW2*t[s][2][1];
            hb[2] = 2*CW0*t[s][4][2] + 2*CW1*t[s][3][2] + CW2*t[s][2][2];
            hb[3] = CW0*(t[s][2][3]+t[s][4][3]) + CW1*(t[s][2][0]+t[s][3][3])
                  + CW2*t[s][2][3];
        } else if (q == 1) {
            hb[0] = CW0*(t[s][2][0]+t[s][4][0]) + CW1*(t[s][1][0]+t[s][3][0])
                  + CW2*t[s][2][0];
            hb[1] = CW0*(t[s][2][1]+t[s][4][1]) + CW1*(t[s][1][1]+t[s][3][1])
                  + CW2*t[s][2][1];
            hb[2] = CW0*(t[s][0][0]+t[s][4][2]) + CW1*(t[s][1][2]+t[s][3][2])
                  + CW2*t[s][2][2];
            hb[3] = CW0*(t[s][1][0]+t[s][4][3]) + CW1*(t[s][2][0]+t[s][4][0])
                  + CW2*t[s][2][3];
        } else if (q == 382) {
            hb[0] = CW0*(t[s][0][0]+t[s][4][2]) + CW1*(t[s][1][0]+t[s][3][0])
                  + CW2*t[s][2][0];
            hb[1] = CW0*(t[s][0][1]+t[s][4][3]) + CW1*(t[s][1][1]+t[s][3][1])
                  + CW2*t[s][2][1];
            hb[2] = CW0*(t[s][0][2]+t[s][2][2]) + CW1*(t[s][1][2]+t[s][3][2])
                  + CW2*t[s][2][2];
            hb[3] = CW0*(t[s][0][3]+t[s][3][0]) + CW1*(t[s][2][0]+t[s][4][2])
                  + CW2*t[s][3][0];
        } else if (q == 383) {
            hb[0] = CW0*(t[s][0][0]+t[s][2][0]) + CW1*(t[s][1][0]+t[s][2][3])
                  + CW2*t[s][2][0];
            hb[1] = 2*CW0*t[s][0][1] + 2*CW1*t[s][1][1] + CW2*t[s][2][1];
            hb[2] = 2*CW0*t[s][0][2] + 2*CW1*t[s][1][2] + CW2*t[s][2][2];
            hb[3] = 2*CW0*t[s][0][3] + 2*CW1*t[s][1][3] + CW2*t[s][2][3];
        }
        h[i] = hb;

        // ---- vertical pass from the register window, store output row i-4
        if (i >= 4) {
            vfloat4 res = CW0 * (h[i - 4] + h[i]) +
                          CW1 * (h[i - 3] + h[i - 1]) +
                          CW2 * h[i - 2];
            __builtin_nontemporal_store(res,
                &((vfloat4*)ob)[(i - 4) * ROWQ + q]);
        }
    }
#undef ISSUE
}

extern "C" void kernel_launch(void* const* d_in, const int* in_sizes, int n_in,
                              void* d_out, int out_size, void* d_ws, size_t ws_size,
                              hipStream_t stream) {
    const float* x = (const float*)d_in[0];
    float* out = (float*)d_out;
    gauss_blur_fused<<<dim3(NBLK), dim3(NT), 0, stream>>>(x, out);
}

// Round 9
// 258.083 us; speedup vs baseline: 1.0777x; 1.0428x over previous
//
#include <hip/hip_runtime.h>

// Separable 5x5 Gaussian blur, sigma=1.1, BORDER_REFLECT_101, NHWC fp32.
// Shape: (64, 384, 512, 3). Row = 512*3 = 1536 floats = 384 float4.
// NOTE: horizontal taps are stride-3 in floats (per-channel, C=3).
//
// == r4 champion (69us kernel) with ONE change: plain cached stores
// instead of __builtin_nontemporal_store. NT stores bypass L2/L3 and
// pay the raw HBM write path per 768B masked store; plain stores let
// the L2 buffer/combine them (fillBuffer sustains 6.6 TB/s this way).
// A/B isolates the store-path hypothesis; everything else identical. ==
//
// Two-tile pipelined, barrier-free, wave-private LDS. One block per
// (batch, 8-row double tile); 512 threads = 8 waves. Wave w owns 48
// output float4 columns (q0=48w) and loads a 64-column window (cols
// q0-2..q0+61, halo included). All 12 input rows (h0-2..h0+9) are
// loaded up front and PINNED with sched_barrier(0) so the compiler
// cannot sink them: tile-2's 4 loads stay in flight (vmcnt>0) under
// tile-1's whole vertical+horizontal phase. Vertical sums go to the
// wave's PRIVATE LDS strip; reflect-101 horizontal pads fixed from the
// wave's own data; horizontal pass (lanes 0..47) reads same-wave LDS
// only -> NO __syncthreads anywhere. Window rows 4..7 are reused for
// tile 2 (12 loads / 8 output rows = 1.5x demand, L3-absorbed).
// XCD swizzle gives each XCD contiguous tiles.

#define BN 64
#define HN 384
#define WN 512
#define CN 3
#define ROWF (WN * CN)              // 1536 floats per row
#define ROWQ (ROWF / 4)             // 384 float4 per row
#define TH 4                        // rows per tile
#define DTH (2 * TH)                // rows per block (double tile)
#define NDT (HN / DTH)              // 48 double-tiles per image
#define NTHR 512                    // 8 waves per block
#define NBLK (BN * NDT)             // 3072 blocks

// Gaussian taps for ksize=5, sigma=1.1 (precomputed, normalized):
#define CW0 0.07076630f
#define CW1 0.24446040f
#define CW2 0.36954650f

typedef float vfloat4 __attribute__((ext_vector_type(4)));

__device__ __forceinline__ void vpass(const float4* win, float* vw, int l) {
#pragma unroll
    for (int r = 0; r < TH; ++r) {
        float4 a;
        a.x = CW0 * (win[r].x + win[r + 4].x) +
              CW1 * (win[r + 1].x + win[r + 3].x) + CW2 * win[r + 2].x;
        a.y = CW0 * (win[r].y + win[r + 4].y) +
              CW1 * (win[r + 1].y + win[r + 3].y) + CW2 * win[r + 2].y;
        a.z = CW0 * (win[r].z + win[r + 4].z) +
              CW1 * (win[r + 1].z + win[r + 3].z) + CW2 * win[r + 2].z;
        a.w = CW0 * (win[r].w + win[r + 4].w) +
              CW1 * (win[r + 1].w + win[r + 3].w) + CW2 * win[r + 2].w;
        ((float4*)(vw + r * 256))[l] = a;
    }
}

__device__ __forceinline__ void pads(float* vw, int q0, int l) {
    // reflect101 horizontal pads, window-float indexed (wf = g - 4*q0 + 8):
    //   wave 0: g=-6..-1 <- {6,7,8,3,4,5}          => wf 2..7 <- {14,15,16,11,12,13}
    //   wave 7: g=1536..1541 <- {1530..32,1527..29} => wf 200..205 <- {194,195,196,191,192,193}
    if (q0 == 0 && l < TH * 6) {
        int r = l / 6, p = l - 6 * r;
        float* vr = vw + r * 256;
        vr[2 + p] = vr[p < 3 ? 14 + p : 8 + p];
    } else if (q0 == 336 && l < TH * 6) {
        int r = l / 6, p = l - 6 * r;
        float* vr = vw + r * 256;
        vr[200 + p] = vr[p < 3 ? 194 + p : 188 + p];
    }
}

__device__ __forceinline__ void hpass(const float* vw, float* ob, int q0, int l) {
    if (l < 48) {
#pragma unroll
        for (int r = 0; r < TH; ++r) {
            const float* vr = vw + r * 256;
            float wnd[20];                 // window floats 4l .. 4l+19
#pragma unroll
            for (int k = 0; k < 5; ++k) {
                float4 t = ((const float4*)vr)[l + k];
                wnd[4 * k + 0] = t.x;
                wnd[4 * k + 1] = t.y;
                wnd[4 * k + 2] = t.z;
                wnd[4 * k + 3] = t.w;
            }
            vfloat4 res;
#pragma unroll
            for (int j = 0; j < 4; ++j) {   // stride-3 taps: per-channel
                res[j] =
                    CW0 * (wnd[j + 2] + wnd[j + 14]) +
                    CW1 * (wnd[j + 5] + wnd[j + 11]) +
                    CW2 * wnd[j + 8];
            }
            // A/B change: plain cached store (was nontemporal_store)
            ((vfloat4*)ob)[r * ROWQ + q0 + l] = res;
        }
    }
}

__global__ __launch_bounds__(NTHR, 6) void gauss_blur_fused(
        const float* __restrict__ x, float* __restrict__ out) {
    // 8 waves * 4 rows * 256 floats = 32768 B, wave-private strips
    __shared__ float v[8 * TH * 256];

    // XCD-contiguous tile swizzle: XCD k (blockIdx%8) gets double-tiles
    // [k*384, (k+1)*384) in linear order.
    const int bid  = blockIdx.x;
    const int tile = (bid & 7) * (NBLK >> 3) + (bid >> 3);
    const int b    = tile / NDT;
    const int h0   = (tile - b * NDT) * DTH;
    const float* __restrict__ xb = x + (size_t)b * HN * ROWF;
    float* __restrict__ ob = out + ((size_t)b * HN + h0) * ROWF;

    const int wid = threadIdx.x >> 6;    // wave 0..7
    const int l   = threadIdx.x & 63;    // lane
    const int q0  = wid * 48;            // first output float4 column
    int c = q0 - 2 + l;                  // this lane's window column
    c = c < 0 ? 0 : (c > ROWQ - 1 ? ROWQ - 1 : c);   // clamp (pads fix edges)

    // ---- all 12 window rows (h0-2 .. h0+9), issued up front and pinned
    float4 win[12];
#pragma unroll
    for (int i = 0; i < 12; ++i) {
        int hs = h0 + i - 2;
        hs = hs < 0 ? -hs : hs;                 // reflect101 low (uniform)
        hs = hs >= HN ? 2 * HN - 2 - hs : hs;   // reflect101 high (uniform)
        win[i] = ((const float4*)(xb + (size_t)hs * ROWF))[c];
    }
    __builtin_amdgcn_sched_barrier(0);   // forbid sinking the loads

    float* const vw = v + wid * (TH * 256);   // this wave's LDS strip

    // ---- tile 1: rows h0 .. h0+3 (uses win[0..7]; win[8..11] in flight)
    vpass(win, vw, l);
    pads(vw, q0, l);
    hpass(vw, ob, q0, l);

    // ---- tile 2: rows h0+4 .. h0+7 (uses win[4..11]); same-wave LDS
    // reuse is ordered by lgkmcnt (no cross-wave sharing -> no barrier)
    vpass(win + 4, vw, l);
    pads(vw, q0, l);
    hpass(vw, ob + TH * ROWF, q0, l);
}

extern "C" void kernel_launch(void* const* d_in, const int* in_sizes, int n_in,
                              void* d_out, int out_size, void* d_ws, size_t ws_size,
                              hipStream_t stream) {
    const float* x = (const float*)d_in[0];
    float* out = (float*)d_out;
    gauss_blur_fused<<<dim3(NBLK), dim3(NTHR), 0, stream>>>(x, out);
}